// Round 10
// baseline (202.290 us; speedup 1.0000x reference)
//
#include <hip/hip_runtime.h>
#include <math.h>

#define BB 16
#define NP 8192
#define NV 42
#define NF 80
#define FEAT 256
#define PPW 64           // points per wave (mvc)
#define WJS 65           // padded LDS stride (65%32==1 -> transposed epilogue conflict-free)

__device__ __forceinline__ float rcp_f(float x)  { return __builtin_amdgcn_rcpf(x); }
__device__ __forceinline__ float rsq_f(float x)  { return __builtin_amdgcn_rsqf(x); }
__device__ __forceinline__ float sqrt_f(float x) { return __builtin_amdgcn_sqrtf(x); }

// theta = 2*asin(x), x in [0,1). Branchless, |err|~1e-5. (validated r2-r9)
__device__ __forceinline__ float theta_from_x(float x) {
  bool big = x > 0.5f;
  float z = big ? fmaf(-0.5f, x, 0.5f) : x * x;
  float s = big ? sqrt_f(z) : x;
  float P = fmaf(z, 0.022371875f, 0.030381944f);
  P = fmaf(z, P, 0.044642857f);
  P = fmaf(z, P, 0.075f);
  P = fmaf(z, P, 0.16666667f);
  float r = fmaf(s * z, P, s);
  return big ? fmaf(-4.f, r, 3.14159265358979f) : 2.f * r;
}

// cold path: runtime face recompute, inside-formula accumulate into own column
__device__ __attribute__((noinline)) void inside_face_rt(
    int f0, int f1, int f2, const float4* vpos,
    float qx, float qy, float qz, float* wjh)   // wjh = own column base
{
  float4 v0 = vpos[f0], v1 = vpos[f1], v2 = vpos[f2];
  float a0x = v0.x - qx, a0y = v0.y - qy, a0z = v0.z - qz;
  float a1x = v1.x - qx, a1y = v1.y - qy, a1z = v1.z - qz;
  float a2x = v2.x - qx, a2y = v2.y - qy, a2z = v2.z - qz;
  float ss0 = fmaf(a0x, a0x, fmaf(a0y, a0y, a0z * a0z));
  float ss1 = fmaf(a1x, a1x, fmaf(a1y, a1y, a1z * a1z));
  float ss2 = fmaf(a2x, a2x, fmaf(a2y, a2y, a2z * a2z));
  float i0 = rsq_f(ss0), i1 = rsq_f(ss1), i2 = rsq_f(ss2);
  float d0 = ss0 * i0, d1 = ss1 * i1, d2 = ss2 * i2;
  float u0x = a0x * i0, u0y = a0y * i0, u0z = a0z * i0;
  float u1x = a1x * i1, u1y = a1y * i1, u1z = a1z * i1;
  float u2x = a2x * i2, u2y = a2y * i2, u2z = a2z * i2;
  float ex = u1x - u2x, ey = u1y - u2y, ez = u1z - u2z;
  float x0 = 0.5f * sqrt_f(fmaf(ex, ex, fmaf(ey, ey, ez * ez)));
  ex = u2x - u0x; ey = u2y - u0y; ez = u2z - u0z;
  float x1 = 0.5f * sqrt_f(fmaf(ex, ex, fmaf(ey, ey, ez * ez)));
  ex = u0x - u1x; ey = u0y - u1y; ez = u0z - u1z;
  float x2 = 0.5f * sqrt_f(fmaf(ex, ex, fmaf(ey, ey, ez * ez)));
  if (x0 >= 1.f) x0 = 0.99999f;
  if (x1 >= 1.f) x1 = 0.99999f;
  if (x2 >= 1.f) x2 = 0.99999f;
  float th0 = theta_from_x(x0), th1 = theta_from_x(x1), th2 = theta_from_x(x2);
  float hh = 0.5f * ((th0 + th1) + th2);
  if (3.14159265358979f - hh < 1e-4f) {
    float cx0 = sqrt_f(fmaxf(fmaf(-x0, x0, 1.f), 0.f));
    float cx1 = sqrt_f(fmaxf(fmaf(-x1, x1, 1.f), 0.f));
    float cx2 = sqrt_f(fmaxf(fmaf(-x2, x2, 1.f), 0.f));
    wjh[f0 * WJS] += (2.f * (x0 * cx0) * d2) * d1;
    wjh[f1 * WJS] += (2.f * (x1 * cx1) * d0) * d2;
    wjh[f2 * WJS] += (2.f * (x2 * cx2) * d1) * d0;
  }
}

// ---------------- Kernel D: MVC weights + deformed ----------------
// 128 threads = 2 INDEPENDENT waves; wave w owns 64 points and runs all 80
// faces for them. No cross-wave merge, no mid-kernel barriers (except init
// and the final cooperative out_w write). LDS/point halves vs r8 -> 2x
// points in flight.
__global__ __launch_bounds__(128) void mvc_kernel(
    const float* __restrict__ src,      // (B,3,N)
    const float* __restrict__ cage_t,   // (B,42,3)
    const float* __restrict__ ncage_t,  // (B,42,3)
    const int* __restrict__ faces,      // (80,3)
    float* __restrict__ out_def,        // (B,3,N)
    float* __restrict__ out_w)          // (B,N,42)
{
  __shared__ float4 vpos[NV];
  __shared__ float4 npos[NV];
  __shared__ int fidp[NF];
  __shared__ float wj[2][NV * WJS];

  const float PI_F = 3.14159265358979323846f;
  int tid  = threadIdx.x;
  int lane = tid & 63;
  int wv   = tid >> 6;
  int b    = blockIdx.x / (NP / 128);
  int pblk = blockIdx.x % (NP / 128);
  int gp   = pblk * 128 + wv * PPW + lane;   // this thread's point

  if (tid < NV) {
    const float* cp = cage_t + (size_t)b * NV * 3 + tid * 3;
    vpos[tid] = make_float4(cp[0], cp[1], cp[2], 0.f);
    const float* np_ = ncage_t + (size_t)b * NV * 3 + tid * 3;
    npos[tid] = make_float4(np_[0], np_[1], np_[2], 0.f);
  }
  if (tid < NF) {
    int f0 = faces[3 * tid], f1 = faces[3 * tid + 1], f2 = faces[3 * tid + 2];
    fidp[tid] = f0 | (f1 << 6) | (f2 << 12);
  }
  for (int i = tid; i < 2 * NV * WJS; i += 128) wj[0][i] = 0.f;
  __syncthreads();

  float qx = src[(size_t)b * 3 * NP + gp];
  float qy = src[(size_t)b * 3 * NP + NP + gp];
  float qz = src[(size_t)b * 3 * NP + 2 * NP + gp];

  int anyInside = 0;
  unsigned long long closeMask = 0ull;
  float* wjh = &wj[wv][lane];

  #pragma unroll 1
  for (int i = 0; i < NF; i++) {
    int pk = fidp[i];
    int f0 = pk & 63, f1 = (pk >> 6) & 63, f2 = pk >> 12;
    float4 v0 = vpos[f0], v1 = vpos[f1], v2 = vpos[f2];
    float a0x = v0.x - qx, a0y = v0.y - qy, a0z = v0.z - qz;
    float a1x = v1.x - qx, a1y = v1.y - qy, a1z = v1.z - qz;
    float a2x = v2.x - qx, a2y = v2.y - qy, a2z = v2.z - qz;
    float ss0 = fmaf(a0x, a0x, fmaf(a0y, a0y, a0z * a0z));
    float ss1 = fmaf(a1x, a1x, fmaf(a1y, a1y, a1z * a1z));
    float ss2 = fmaf(a2x, a2x, fmaf(a2y, a2y, a2z * a2z));
    if (ss0 < 1e-16f) closeMask |= (1ull << f0);   // d<1e-8 <=> ss<1e-16
    if (ss1 < 1e-16f) closeMask |= (1ull << f1);
    if (ss2 < 1e-16f) closeMask |= (1ull << f2);
    float i0 = rsq_f(ss0), i1 = rsq_f(ss1), i2 = rsq_f(ss2);
    float d0 = ss0 * i0, d1 = ss1 * i1, d2 = ss2 * i2;
    float u0x = a0x * i0, u0y = a0y * i0, u0z = a0z * i0;
    float u1x = a1x * i1, u1y = a1y * i1, u1z = a1z * i1;
    float u2x = a2x * i2, u2y = a2y * i2, u2z = a2z * i2;
    // chord half-lengths via EDGE SUBTRACTION (r7 lesson: never 1-u.u')
    float ex = u1x - u2x, ey = u1y - u2y, ez = u1z - u2z;
    float x0 = 0.5f * sqrt_f(fmaf(ex, ex, fmaf(ey, ey, ez * ez)));
    ex = u2x - u0x; ey = u2y - u0y; ez = u2z - u0z;
    float x1 = 0.5f * sqrt_f(fmaf(ex, ex, fmaf(ey, ey, ez * ez)));
    ex = u0x - u1x; ey = u0y - u1y; ez = u0z - u1z;
    float x2 = 0.5f * sqrt_f(fmaf(ex, ex, fmaf(ey, ey, ez * ez)));
    if (x0 >= 1.f) x0 = 0.99999f;     // reference clamp l>=2 -> 1.99998
    if (x1 >= 1.f) x1 = 0.99999f;
    if (x2 >= 1.f) x2 = 0.99999f;
    float cx0 = sqrt_f(fmaxf(fmaf(-x0, x0, 1.f), 0.f));
    float cx1 = sqrt_f(fmaxf(fmaf(-x1, x1, 1.f), 0.f));
    float cx2 = sqrt_f(fmaxf(fmaf(-x2, x2, 1.f), 0.f));
    float th0 = theta_from_x(x0);
    float th1 = theta_from_x(x1);
    float th2 = theta_from_x(x2);
    float hh = 0.5f * ((th0 + th1) + th2);
    if (PI_F - hh < 1e-4f) anyInside = 1;
    float t0 = x0 * cx0, t1 = x1 * cx1, t2 = x2 * cx2;
    float st0 = t0 + t0, st1 = t1 + t1, st2 = t2 + t2;   // sin(theta_i)
    float A1 = x0 * (cx1 * cx2);
    float A2 = x1 * (cx0 * cx2);
    float A3 = x2 * (cx0 * cx1);
    float A4 = x0 * (x1 * x2);
    float sh  = ((A1 + A2) + A3) - A4;     // sin(h)
    float sm0 = ((-A1 + A2) + A3) + A4;    // sin(h-th0)
    float sm1 = ((A1 - A2) + A3) + A4;
    float sm2 = ((A1 + A2) - A3) + A4;
    float twosh = sh + sh;
    float c0 = fmaf(twosh * sm0, rcp_f(st1 * st2), -1.f);
    float c1 = fmaf(twosh * sm1, rcp_f(st2 * st0), -1.f);
    float c2 = fmaf(twosh * sm2, rcp_f(st0 * st1), -1.f);
    c0 = fminf(fmaxf(c0, -0.99999f), 0.99999f);
    c1 = fminf(fmaxf(c1, -0.99999f), 0.99999f);
    c2 = fminf(fmaxf(c2, -0.99999f), 0.99999f);
    float det = u0x * fmaf(u1y, u2z, -(u1z * u2y))
              - u0y * fmaf(u1x, u2z, -(u1z * u2x))
              + u0z * fmaf(u1x, u2y, -(u1y * u2x));
    float sg = (det > 0.f) ? 1.f : ((det < 0.f) ? -1.f : 0.f);
    float sn0 = sg * sqrt_f(fmaf(-c0, c0, 1.f));
    float sn1 = sg * sqrt_f(fmaf(-c1, c1, 1.f));
    float sn2 = sg * sqrt_f(fmaf(-c2, c2, 1.f));
    float w0 = fmaf(-c2, th1, fmaf(-c1, th2, th0)) * rcp_f((d0 * st1) * sn2);
    float w1 = fmaf(-c0, th2, fmaf(-c2, th0, th1)) * rcp_f((d1 * st2) * sn0);
    float w2 = fmaf(-c1, th0, fmaf(-c0, th1, th2)) * rcp_f((d2 * st0) * sn1);
    wjh[f0 * WJS] += w0;      // own column: no atomics, no cross-wave merge
    wjh[f1 * WJS] += w1;
    wjh[f2 * WJS] += w2;
  }

  if (anyInside) {   // cold: exact `where(inside, ...)` semantics
    for (int c = 0; c < NV; c++) wjh[c * WJS] = 0.f;
    #pragma unroll 1
    for (int i = 0; i < NF; i++) {
      int pk = fidp[i];
      inside_face_rt(pk & 63, (pk >> 6) & 63, pk >> 12, vpos, qx, qy, qz, wjh);
    }
  }

  // per-point epilogue (own wave only; no barrier needed)
  {
    float sum = 0.f;
    if (closeMask) {   // cold: query coincides with a cage vertex
      for (int c = 0; c < NV; c++) {
        float w = ((closeMask >> c) & 1ull) ? 1.f : 0.f;
        wjh[c * WJS] = w;
        sum += w;
      }
    } else {
      for (int c = 0; c < NV; c++) sum += wjh[c * WJS];
    }
    if (sum == 0.f) sum = 1.f;
    float inv = rcp_f(sum);
    float ax = 0.f, ay = 0.f, az = 0.f;
    for (int c = 0; c < NV; c++) {
      float w = wjh[c * WJS] * inv;
      wjh[c * WJS] = w;
      float4 n = npos[c];
      ax = fmaf(w, n.x, ax);
      ay = fmaf(w, n.y, ay);
      az = fmaf(w, n.z, az);
    }
    out_def[(size_t)b * 3 * NP + gp]          = ax;
    out_def[(size_t)b * 3 * NP + NP + gp]     = ay;
    out_def[(size_t)b * 3 * NP + 2 * NP + gp] = az;
  }
  __syncthreads();

  // coalesced weight write for all 128 points of the block
  float* wbase = out_w + ((size_t)b * NP + pblk * 128) * NV;
  for (int idx = tid; idx < 128 * NV; idx += 128) {
    int pp = idx / NV;
    int c  = idx - pp * NV;
    wbase[idx] = wj[pp >> 6][c * WJS + (pp & 63)];
  }
}

// ---------------- shared split-K linear body (round-3 proven) ----------------
__device__ __forceinline__ void splitk_body(
    const float* in0, const float* in1,
    const float* W, const float* bias, float* out,
    int FI, int FO, int relu, int ox, int bb, int tid,
    float* sIn, float (*part)[64])
{
  for (int i = tid; i < FI; i += 256) {
    float v;
    if (in1) v = (i < FEAT) ? in0[(size_t)bb * FEAT + i]
                            : in1[(size_t)bb * FEAT + i - FEAT];
    else     v = in0[(size_t)bb * FI + i];
    sIn[i] = v;
  }
  __syncthreads();
  int o = ox * 64 + (tid & 63);
  int kk = tid >> 6;
  int seg = FI >> 2;
  float acc = 0.f;
  const float* wp = W + o;
  #pragma unroll 4
  for (int i = kk * seg; i < (kk + 1) * seg; i++)
    acc = fmaf(sIn[i], wp[(size_t)i * FO], acc);
  part[kk][tid & 63] = acc;
  __syncthreads();
  if (tid < 64) {
    float r = ((part[0][tid] + part[1][tid]) + (part[2][tid] + part[3][tid]))
              + bias[o];
    out[(size_t)bb * FO + o] = relu ? fmaxf(r, 0.f) : r;
  }
}

// ---------------- Kernel A: cage_opt (blocks<672) + L1 split-K (672..799) ----
__global__ __launch_bounds__(256) void cage_l1_kernel(
    const float* __restrict__ tmpl, const float* __restrict__ src,
    const float* __restrict__ sf, const float* __restrict__ tf,
    const float* __restrict__ W1, const float* __restrict__ b1,
    float* __restrict__ cage, float* __restrict__ h1)
{
  __shared__ float red[8];
  __shared__ float sIn[512];
  __shared__ float part[4][64];
  int tid = threadIdx.x;

  if (blockIdx.x < BB * NV) {
    int b = blockIdx.x / NV;
    int v = blockIdx.x % NV;
    const float* sp = src + (size_t)b * 3 * NP;
    float cx = tmpl[v], cy = tmpl[NV + v], cz = tmpl[2 * NV + v];
    int k = 0;
    while (true) {
      float m = 3.4e38f;
      for (int i = tid; i < NP; i += 256) {
        float dx = __fsub_rn(cx, sp[i]);
        float dy = __fsub_rn(cy, sp[NP + i]);
        float dz = __fsub_rn(cz, sp[2 * NP + i]);
        float ss = __fadd_rn(__fadd_rn(__fmul_rn(dx, dx), __fmul_rn(dy, dy)),
                             __fmul_rn(dz, dz));
        m = fminf(m, ss);
      }
      #pragma unroll
      for (int off = 32; off > 0; off >>= 1)
        m = fminf(m, __shfl_down(m, off, 64));
      int wid = tid >> 6;
      __syncthreads();
      if ((tid & 63) == 0) red[wid] = m;
      __syncthreads();
      if (tid == 0) {
        float mm = fminf(fminf(red[0], red[1]), fminf(red[2], red[3]));
        red[4] = sqrtf(mm);
      }
      __syncthreads();
      float mind = red[4];
      if (mind > 0.4f && k < 100) {
        cx = __fsub_rn(cx, __fmul_rn(0.01f, cx));
        cy = __fsub_rn(cy, __fmul_rn(0.01f, cy));
        cz = __fsub_rn(cz, __fmul_rn(0.01f, cz));
        k++;
      } else {
        break;
      }
    }
    if (tid == 0) {
      cage[(size_t)b * 3 * NV + v]          = cx;
      cage[(size_t)b * 3 * NV + NV + v]     = cy;
      cage[(size_t)b * 3 * NV + 2 * NV + v] = cz;
    }
  } else {
    int idx = blockIdx.x - BB * NV;   // 0..127
    splitk_body(sf, tf, W1, b1, h1, 512, 512, 1, idx & 7, idx >> 3,
                tid, sIn, part);
  }
}

// ---------------- fused MLP tail: L2 -> L3 -> L4 + cage finalize ----------
// grid = BB blocks, 256 threads; intermediates live in LDS.
__global__ __launch_bounds__(256) void mlp_tail_kernel(
    const float* __restrict__ h1,     // (B,512)
    const float* __restrict__ W2, const float* __restrict__ b2,
    const float* __restrict__ W3, const float* __restrict__ b3,
    const float* __restrict__ W4, const float* __restrict__ b4,
    const float* __restrict__ cage,   // (B,3,42)
    float* __restrict__ out_io,       // (B,126)
    float* __restrict__ cage_t,       // (B,42,3)
    float* __restrict__ ncage_t)      // (B,42,3)
{
  __shared__ float sA[512];
  __shared__ float sB[512];
  int bb = blockIdx.x;
  int tid = threadIdx.x;
  sA[tid]       = h1[(size_t)bb * 512 + tid];
  sA[tid + 256] = h1[(size_t)bb * 512 + tid + 256];
  __syncthreads();
  // L2: 512 -> 512 (2 outputs/thread)
  {
    int o0 = tid, o1 = tid + 256;
    float a0 = b2[o0], a1 = b2[o1];
    #pragma unroll 4
    for (int i = 0; i < 512; i++) {
      float s = sA[i];
      a0 = fmaf(s, W2[(size_t)i * 512 + o0], a0);
      a1 = fmaf(s, W2[(size_t)i * 512 + o1], a1);
    }
    sB[o0] = fmaxf(a0, 0.f);
    sB[o1] = fmaxf(a1, 0.f);
  }
  __syncthreads();
  // L3: 512 -> 256 (1 output/thread)
  {
    float a0 = b3[tid];
    #pragma unroll 4
    for (int i = 0; i < 512; i++)
      a0 = fmaf(sB[i], W3[(size_t)i * 256 + tid], a0);
    sA[tid] = fmaxf(a0, 0.f);
  }
  __syncthreads();
  // L4: 256 -> 126 + cage finalize
  if (tid < 126) {
    float acc = b4[tid];
    const float* wp = W4 + tid;
    #pragma unroll 4
    for (int i = 0; i < 256; i++) acc = fmaf(sA[i], wp[(size_t)i * 126], acc);
    out_io[(size_t)bb * 126 + tid] = acc;
    float c  = cage[(size_t)bb * 126 + tid];
    float nc = c + acc;
    int d = tid / NV, v = tid - d * NV;
    cage_t[(size_t)bb * NV * 3 + v * 3 + d]  = c;
    ncage_t[(size_t)bb * NV * 3 + v * 3 + d] = nc;
  }
}

extern "C" void kernel_launch(void* const* d_in, const int* in_sizes, int n_in,
                              void* d_out, int out_size, void* d_ws, size_t ws_size,
                              hipStream_t stream) {
  (void)in_sizes; (void)n_in; (void)out_size; (void)d_ws; (void)ws_size;
  const float* src   = (const float*)d_in[0];
  const float* sf    = (const float*)d_in[2];
  const float* tf    = (const float*)d_in[3];
  const float* tmpl  = (const float*)d_in[4];
  const int*   faces = (const int*)d_in[5];
  const float* W1 = (const float*)d_in[6];  const float* b1 = (const float*)d_in[7];
  const float* W2 = (const float*)d_in[8];  const float* b2 = (const float*)d_in[9];
  const float* W3 = (const float*)d_in[10]; const float* b3 = (const float*)d_in[11];
  const float* W4 = (const float*)d_in[12]; const float* b4 = (const float*)d_in[13];

  float* out = (float*)d_out;
  float* out_cage_t  = out;                 // (16,42,3)   2016
  float* out_ncage_t = out + 2016;          // (16,42,3)   2016
  float* out_def     = out + 4032;          // (16,3,8192) 393216
  float* out_w       = out + 397248;        // (16,8192,42) 5505024
  float* out_io      = out + 5902272;       // (16,126)    2016

  // scratch carved out of the weights region (fully overwritten by mvc_kernel)
  float* s_cage = out_w;           // 2016
  float* s_h1   = out_w + 2016;    // 8192

  cage_l1_kernel<<<dim3(BB * NV + 128), dim3(256), 0, stream>>>(
      tmpl, src, sf, tf, W1, b1, s_cage, s_h1);
  mlp_tail_kernel<<<dim3(BB), dim3(256), 0, stream>>>(
      s_h1, W2, b2, W3, b3, W4, b4, s_cage, out_io, out_cage_t, out_ncage_t);
  mvc_kernel<<<dim3(BB * (NP / 128)), dim3(128), 0, stream>>>(
      src, out_cage_t, out_ncage_t, faces, out_def, out_w);
}